// Round 1
// baseline (43.322 us; speedup 1.0000x reference)
//
#include <hip/hip_runtime.h>

#define B_CONST 4
#define N_CONST 4096
#define CHUNK 512
#define INF_F __int_as_float(0x7F800000)

// ---------------- init: zero the output scalar, set min buffers to +inf bits
__global__ void chamfer_init_kernel(float* out, unsigned* mins, int n_mins) {
    int idx = blockIdx.x * blockDim.x + threadIdx.x;
    if (idx == 0) out[0] = 0.0f;
    for (int i = idx; i < n_mins; i += gridDim.x * blockDim.x)
        mins[i] = 0x7F800000u;  // +inf
}

// ---------------- per-X-point min over a chunk of Y points staged in LDS
// USE_MASK: add +inf penalty for invalid Y (gt) points (direction 1)
template <bool USE_MASK>
__global__ void chamfer_min_kernel(const float* __restrict__ X,
                                   const float* __restrict__ Y,
                                   const int* __restrict__ maskY,
                                   unsigned* __restrict__ out_min,
                                   int Nx, int Ny) {
    __shared__ float sy[CHUNK * 3];
    __shared__ float sw[CHUNK];

    const int b = blockIdx.z;
    const int x_idx = blockIdx.x * blockDim.x + threadIdx.x;
    const int cbase = blockIdx.y * CHUNK;

    const float* Xb = X + (size_t)b * Nx * 3;
    const float* Yb = Y + (size_t)b * Ny * 3;

    // stage Y chunk (coalesced flat copy)
    for (int t = threadIdx.x; t < CHUNK * 3; t += blockDim.x)
        sy[t] = Yb[(size_t)cbase * 3 + t];
    if (USE_MASK) {
        for (int t = threadIdx.x; t < CHUNK; t += blockDim.x)
            sw[t] = maskY[(size_t)b * Ny + cbase + t] ? 0.0f : INF_F;
    }
    __syncthreads();

    const float x0 = Xb[x_idx * 3 + 0];
    const float x1 = Xb[x_idx * 3 + 1];
    const float x2 = Xb[x_idx * 3 + 2];

    // 4 independent min accumulators to break the fmin dependency chain
    float m0 = INF_F, m1 = INF_F, m2 = INF_F, m3 = INF_F;
    #pragma unroll 4
    for (int k = 0; k < CHUNK; k += 4) {
        {
            float d0 = x0 - sy[(k + 0) * 3 + 0];
            float d1 = x1 - sy[(k + 0) * 3 + 1];
            float d2 = x2 - sy[(k + 0) * 3 + 2];
            float d = d0 * d0 + d1 * d1 + d2 * d2;
            if (USE_MASK) d += sw[k + 0];
            m0 = fminf(m0, d);
        }
        {
            float d0 = x0 - sy[(k + 1) * 3 + 0];
            float d1 = x1 - sy[(k + 1) * 3 + 1];
            float d2 = x2 - sy[(k + 1) * 3 + 2];
            float d = d0 * d0 + d1 * d1 + d2 * d2;
            if (USE_MASK) d += sw[k + 1];
            m1 = fminf(m1, d);
        }
        {
            float d0 = x0 - sy[(k + 2) * 3 + 0];
            float d1 = x1 - sy[(k + 2) * 3 + 1];
            float d2 = x2 - sy[(k + 2) * 3 + 2];
            float d = d0 * d0 + d1 * d1 + d2 * d2;
            if (USE_MASK) d += sw[k + 2];
            m2 = fminf(m2, d);
        }
        {
            float d0 = x0 - sy[(k + 3) * 3 + 0];
            float d1 = x1 - sy[(k + 3) * 3 + 1];
            float d2 = x2 - sy[(k + 3) * 3 + 2];
            float d = d0 * d0 + d1 * d1 + d2 * d2;
            if (USE_MASK) d += sw[k + 3];
            m3 = fminf(m3, d);
        }
    }
    float m = fminf(fminf(m0, m1), fminf(m2, m3));

    // squared distances are >= 0, so float ordering == uint ordering
    atomicMin(&out_min[(size_t)b * Nx + x_idx], __float_as_uint(m));
}

// ---------------- final reduce: sum minA (all) + minB (masked) -> out[0]
__global__ void chamfer_reduce_kernel(const unsigned* __restrict__ minA,
                                      const unsigned* __restrict__ minB,
                                      const int* __restrict__ mask,
                                      float* __restrict__ out,
                                      int nA, int nB) {
    float acc = 0.0f;
    const int total = nA + nB;
    for (int i = blockIdx.x * blockDim.x + threadIdx.x; i < total;
         i += gridDim.x * blockDim.x) {
        if (i < nA) {
            acc += __uint_as_float(minA[i]);
        } else {
            int j = i - nA;
            if (mask[j]) acc += __uint_as_float(minB[j]);
        }
    }
    // wave64 shuffle reduce
    #pragma unroll
    for (int off = 32; off > 0; off >>= 1)
        acc += __shfl_down(acc, off, 64);
    __shared__ float wsum[4];  // 256 threads = 4 waves
    int wave = threadIdx.x >> 6;
    if ((threadIdx.x & 63) == 0) wsum[wave] = acc;
    __syncthreads();
    if (threadIdx.x == 0) {
        atomicAdd(out, wsum[0] + wsum[1] + wsum[2] + wsum[3]);
    }
}

extern "C" void kernel_launch(void* const* d_in, const int* in_sizes, int n_in,
                              void* d_out, int out_size, void* d_ws, size_t ws_size,
                              hipStream_t stream) {
    const float* preds = (const float*)d_in[0];  // [B, Npred, 3]
    const float* gts   = (const float*)d_in[1];  // [B, Ngt, 3]
    const int*   mask  = (const int*)d_in[2];    // [B, Ngt] (0/1)
    float* out = (float*)d_out;

    const int B = B_CONST, Npred = N_CONST, Ngt = N_CONST;

    unsigned* minA = (unsigned*)d_ws;            // [B*Npred] min over valid gts
    unsigned* minB = minA + (size_t)B * Npred;   // [B*Ngt]   min over all preds
    const int n_mins = B * Npred + B * Ngt;

    chamfer_init_kernel<<<128, 256, 0, stream>>>(out, minA, n_mins);

    // Direction 1: for each pred, min over VALID gts (mask penalty)
    {
        dim3 grid(Npred / 256, Ngt / CHUNK, B);
        chamfer_min_kernel<true><<<grid, 256, 0, stream>>>(
            preds, gts, mask, minA, Npred, Ngt);
    }
    // Direction 2: for each gt, min over ALL preds
    {
        dim3 grid(Ngt / 256, Npred / CHUNK, B);
        chamfer_min_kernel<false><<<grid, 256, 0, stream>>>(
            gts, preds, nullptr, minB, Ngt, Npred);
    }

    chamfer_reduce_kernel<<<64, 256, 0, stream>>>(
        minA, minB, mask, out, B * Npred, B * Ngt);
}

// Round 5
// 22.566 us; speedup vs baseline: 1.9198x; 1.9198x over previous
//
#include <hip/hip_runtime.h>

#define NBATCH 4
#define NPTS   4096
#define YCHUNK 512
#define XCHUNK 512              // 256 threads x 2 points each
#define NYC    (NPTS / YCHUNK)  // 8
#define NXC    (NPTS / XCHUNK)  // 8
#define BIGF   1e30f

// Fused both-direction chamfer partial-min kernel.
// grid = (NXC, NYC, 2*NBATCH); block = 256.
// dir 0: X=preds, Y=gts (mask folded into ry as +BIGF penalty)
// dir 1: X=gts,   Y=preds (no inner mask; applied at reduce)
// partial[((dir*NBATCH + b)*NYC + yc)*NPTS + x] = rx + min_{j in chunk}(ry_j - 2 x.y_j)
__global__ __launch_bounds__(256)
void chamfer_min_kernel(const float* __restrict__ preds,
                        const float* __restrict__ gts,
                        const int* __restrict__ mask,
                        float* __restrict__ partial,
                        float* __restrict__ out) {
    const int zc  = blockIdx.z;
    const int dir = zc >> 2;
    const int b   = zc & 3;
    const int tid = threadIdx.x;

    // zero the output scalar exactly once; the reduce kernel (next dispatch,
    // same stream) accumulates after this kernel fully completes.
    if ((zc | blockIdx.x | blockIdx.y | tid) == 0) out[0] = 0.0f;

    const float* X = (dir == 0 ? preds : gts) + (size_t)b * NPTS * 3;
    const float* Y = (dir == 0 ? gts : preds) + (size_t)b * NPTS * 3;

    __shared__ float4 sy[YCHUNK];
    const int cbase = blockIdx.y * YCHUNK;
    for (int t = tid; t < YCHUNK; t += 256) {
        const int j = cbase + t;
        const float y0 = Y[j * 3 + 0];
        const float y1 = Y[j * 3 + 1];
        const float y2 = Y[j * 3 + 2];
        float ry = y0 * y0 + y1 * y1 + y2 * y2;
        if (dir == 0 && mask[b * NPTS + j] == 0) ry = BIGF;
        sy[t] = make_float4(y0, y1, y2, ry);
    }
    __syncthreads();

    const int xA = blockIdx.x * XCHUNK + tid;
    const int xB = xA + 256;
    float a0 = X[xA * 3 + 0], a1 = X[xA * 3 + 1], a2 = X[xA * 3 + 2];
    float c0 = X[xB * 3 + 0], c1 = X[xB * 3 + 1], c2 = X[xB * 3 + 2];
    const float rxA = a0 * a0 + a1 * a1 + a2 * a2;
    const float rxB = c0 * c0 + c1 * c1 + c2 * c2;
    // pre-scale so inner loop is pure fma: t = ry + (-2x0)*y0 + (-2x1)*y1 + (-2x2)*y2
    a0 *= -2.0f; a1 *= -2.0f; a2 *= -2.0f;
    c0 *= -2.0f; c1 *= -2.0f; c2 *= -2.0f;

    float mA0 = BIGF, mA1 = BIGF;
    float mB0 = BIGF, mB1 = BIGF;

    #pragma unroll 4
    for (int k = 0; k < YCHUNK; k += 4) {
        const float4 p0 = sy[k + 0];
        const float4 p1 = sy[k + 1];
        const float4 p2 = sy[k + 2];
        const float4 p3 = sy[k + 3];

        const float tA0 = fmaf(a0, p0.x, fmaf(a1, p0.y, fmaf(a2, p0.z, p0.w)));
        const float tA1 = fmaf(a0, p1.x, fmaf(a1, p1.y, fmaf(a2, p1.z, p1.w)));
        const float tA2 = fmaf(a0, p2.x, fmaf(a1, p2.y, fmaf(a2, p2.z, p2.w)));
        const float tA3 = fmaf(a0, p3.x, fmaf(a1, p3.y, fmaf(a2, p3.z, p3.w)));
        mA0 = fminf(mA0, fminf(tA0, tA1));   // -> v_min3_f32
        mA1 = fminf(mA1, fminf(tA2, tA3));

        const float tB0 = fmaf(c0, p0.x, fmaf(c1, p0.y, fmaf(c2, p0.z, p0.w)));
        const float tB1 = fmaf(c0, p1.x, fmaf(c1, p1.y, fmaf(c2, p1.z, p1.w)));
        const float tB2 = fmaf(c0, p2.x, fmaf(c1, p2.y, fmaf(c2, p2.z, p2.w)));
        const float tB3 = fmaf(c0, p3.x, fmaf(c1, p3.y, fmaf(c2, p3.z, p3.w)));
        mB0 = fminf(mB0, fminf(tB0, tB1));
        mB1 = fminf(mB1, fminf(tB2, tB3));
    }

    const float dA = rxA + fminf(mA0, mA1);
    const float dB = rxB + fminf(mB0, mB1);

    float* prow = partial + ((size_t)(dir * NBATCH + b) * NYC + blockIdx.y) * NPTS;
    prow[blockIdx.x * XCHUNK + tid] = dA;
    prow[blockIdx.x * XCHUNK + tid + 256] = dB;
}

// Final reduce: min over the NYC chunk-partials per point, mask dir-1 (gt side),
// sum everything into out[0].
// grid = (2*NBATCH*NPTS)/256 = 128 blocks; block = 256.
__global__ __launch_bounds__(256)
void chamfer_reduce_kernel(const float* __restrict__ partial,
                           const int* __restrict__ mask,
                           float* __restrict__ out) {
    const int gid = blockIdx.x * blockDim.x + threadIdx.x;
    const int dir = gid >> 14;          // / (NBATCH*NPTS)
    const int rem = gid & 16383;
    const int b   = rem >> 12;
    const int x   = rem & 4095;

    const float* p = partial + ((size_t)(dir * NBATCH + b) * NYC) * NPTS + x;
    float m = p[0];
    #pragma unroll
    for (int c = 1; c < NYC; ++c) m = fminf(m, p[(size_t)c * NPTS]);

    float v = m;
    if (dir == 1 && mask[b * NPTS + x] == 0) v = 0.0f;

    // wave64 shuffle reduce
    #pragma unroll
    for (int off = 32; off > 0; off >>= 1)
        v += __shfl_down(v, off, 64);

    __shared__ float wsum[4];
    const int wave = threadIdx.x >> 6;
    if ((threadIdx.x & 63) == 0) wsum[wave] = v;
    __syncthreads();
    if (threadIdx.x == 0)
        atomicAdd(out, wsum[0] + wsum[1] + wsum[2] + wsum[3]);
}

extern "C" void kernel_launch(void* const* d_in, const int* in_sizes, int n_in,
                              void* d_out, int out_size, void* d_ws, size_t ws_size,
                              hipStream_t stream) {
    const float* preds = (const float*)d_in[0];  // [B, Npred, 3]
    const float* gts   = (const float*)d_in[1];  // [B, Ngt, 3]
    const int*   mask  = (const int*)d_in[2];    // [B, Ngt]
    float* out = (float*)d_out;

    float* partial = (float*)d_ws;  // [2][NBATCH][NYC][NPTS] = 1 MB

    dim3 grid(NXC, NYC, 2 * NBATCH);
    chamfer_min_kernel<<<grid, 256, 0, stream>>>(preds, gts, mask, partial, out);

    chamfer_reduce_kernel<<<(2 * NBATCH * NPTS) / 256, 256, 0, stream>>>(
        partial, mask, out);
}